// Round 6
// baseline (5383.398 us; speedup 1.0000x reference)
//
#include <hip/hip_runtime.h>
#include <hip/hip_bf16.h>

// LightGCN 3-hop GraphConv (M4_86749749444857).
// R11->R12: band-sweep reverted (rate-desync by row degree; no spmm gain, fine
// +50us). Sort pipeline = R9 exact (512-row buckets), except es keeps the row
// bits. SpMM replaced by LDS-accumulate blocks: 256 threads own 128 rows and
// their contiguous es range; quarter-wave per edge, lane owns 4 dims,
// ds_add_f32 into a padded 128x68 f32 LDS tile. Zero degree-divergence, fully
// sequential es stream, coalesced writeback.

#define D 64
typedef unsigned short u16;

#define NBP   512    // padded bucket count (real NB = ceil(n/512) = 293)
#define BSH   9      // 512 rows/bucket
#define TILE  2048   // edges per coarse block
#define FCAP  4608   // fine LDS chunk slots (128 rows x 32 mean = 4096 + 8 sigma)
#define YP    68     // padded LDS row stride (floats) -- breaks 4-quarter bank clash

__device__ __forceinline__ float bf2f(u16 h) {
    union { unsigned int u; float f; } c;
    c.u = ((unsigned int)h) << 16;
    return c.f;
}
__device__ __forceinline__ u16 f2bf(float f) {
    union { float f; unsigned int u; } c; c.f = f;
    unsigned int r = c.u + 0x7FFFu + ((c.u >> 16) & 1u);  // RNE
    return (u16)(r >> 16);
}

struct U4 { u16 a, b, c, d; } __attribute__((aligned(8)));

// ---------------- dtype sniffing ----------------
__global__ void detect_kernel(const u16* __restrict__ emb,
                              const u16* __restrict__ vals,
                              int* __restrict__ flags) {
    int lane = threadIdx.x;  // 64 threads, 1 block
    int se = 0, sv = 0;
    for (int k = 0; k < 16; ++k) {
        int idx = (lane * 16 + k) * 2;
        u16 he = emb[idx];
        int ee = (he >> 7) & 0xFF;
        if (ee >= 100 && ee < 127) se++;
        u16 hv = vals[idx];
        int ev = (hv >> 7) & 0xFF;
        if ((hv >> 15) == 0 && ev >= 60 && ev < 123) sv++;
    }
    atomicAdd(&flags[0], se);
    atomicAdd(&flags[1], sv);
}

// ---------------- ego -> bf16 X0 ----------------
__global__ __launch_bounds__(256)
void convert_kernel(const void* __restrict__ ue, const void* __restrict__ ie,
                    const int* __restrict__ flags, u16* __restrict__ x0,
                    int total, int usz) {
    int i = (blockIdx.x * blockDim.x + threadIdx.x) * 4;
    if (i >= total) return;
    const void* src = (i < usz) ? ue : ie;
    int off = (i < usz) ? i : i - usz;
    U4 o;
    if (flags[0] >= 512) {
        o = *(const U4*)((const u16*)src + off);
    } else {
        const float4 v = *(const float4*)((const float*)src + off);
        o.a = f2bf(v.x); o.b = f2bf(v.y); o.c = f2bf(v.z); o.d = f2bf(v.w);
    }
    *(U4*)(x0 + i) = o;
}

// ---------------- bucket histogram (LDS-aggregated) ----------------
__global__ __launch_bounds__(256)
void bhist_kernel(const int* __restrict__ row, int* __restrict__ bcnt, int nnz) {
    __shared__ int h[NBP];
    int t = threadIdx.x;
    h[t] = 0; h[t + 256] = 0;
    __syncthreads();
    for (int i = blockIdx.x * 256 + t; i < nnz; i += gridDim.x * 256)
        atomicAdd(&h[row[i] >> BSH], 1);
    __syncthreads();
    if (h[t])       atomicAdd(&bcnt[t],       h[t]);
    if (h[t + 256]) atomicAdd(&bcnt[t + 256], h[t + 256]);
}

// single block, 512 threads: exclusive scan of bucket counts
__global__ void bscan_kernel(const int* __restrict__ bcnt, int* __restrict__ bbase,
                             int* __restrict__ bcursor, int nb, int nnz) {
    __shared__ int buf[NBP];
    int t = threadIdx.x;
    int v = (t < nb) ? bcnt[t] : 0;
    buf[t] = v;
    __syncthreads();
    for (int off = 1; off < NBP; off <<= 1) {
        int y = (t >= off) ? buf[t - off] : 0;
        __syncthreads();
        buf[t] += y;
        __syncthreads();
    }
    int excl = buf[t] - v;
    bbase[t] = excl;
    bcursor[t] = excl;
    if (t == 0) bbase[nb] = nnz;
}

// ---------------- coarse sort: COO -> bucket-grouped es2 ----------------
// es2 entry: .x = (row&511)<<18 | col   .y = val bits
__global__ __launch_bounds__(256)
void coarse_kernel(const int* __restrict__ row, const int* __restrict__ col,
                   const void* __restrict__ vals, const int* __restrict__ flags,
                   int* __restrict__ bcursor, int2* __restrict__ es2, int nnz) {
    __shared__ int2 ebuf[TILE];
    __shared__ u16  slotb[TILE];
    __shared__ int  hcnt[NBP], hscn[NBP], goff[NBP];
    int t = threadIdx.x;
    int base = blockIdx.x * TILE;
    int tcnt = nnz - base; if (tcnt > TILE) tcnt = TILE;
    bool vbf = (flags[1] >= 512);

    hcnt[t] = 0; hcnt[t + 256] = 0;
    __syncthreads();

    int eb[8], er[8], ep[8], ev[8];
#pragma unroll
    for (int k = 0; k < 8; ++k) {
        int i = base + k * 256 + t;
        eb[k] = -1;
        if (k * 256 + t < tcnt) {
            int r = row[i];
            int c = col[i];
            float v = vbf ? bf2f(((const u16*)vals)[i]) : ((const float*)vals)[i];
            eb[k] = r >> BSH;
            ep[k] = ((r & 511) << 18) | c;
            ev[k] = __float_as_int(v);
            er[k] = atomicAdd(&hcnt[eb[k]], 1);
        }
    }
    __syncthreads();
    hscn[t] = hcnt[t]; hscn[t + 256] = hcnt[t + 256];
    __syncthreads();
    for (int off = 1; off < NBP; off <<= 1) {
        int a0 = (t >= off) ? hscn[t - off] : 0;
        int a1 = (t + 256 >= off) ? hscn[t + 256 - off] : 0;
        __syncthreads();
        hscn[t] += a0; hscn[t + 256] += a1;
        __syncthreads();
    }
#pragma unroll
    for (int k = 0; k < 8; ++k) {
        if (eb[k] >= 0) {
            int slot = hscn[eb[k]] - hcnt[eb[k]] + er[k];
            ebuf[slot] = make_int2(ep[k], ev[k]);
            slotb[slot] = (u16)eb[k];
        }
    }
    __syncthreads();
    if (hcnt[t] > 0)       goff[t]       = atomicAdd(&bcursor[t],       hcnt[t]);
    if (hcnt[t + 256] > 0) goff[t + 256] = atomicAdd(&bcursor[t + 256], hcnt[t + 256]);
    __syncthreads();
#pragma unroll
    for (int k = 0; k < 8; ++k) {
        int p = k * 256 + t;
        if (p < tcnt) {
            int b = slotb[p];
            int dest = goff[b] + (p - (hscn[b] - hcnt[b]));
            es2[dest] = ebuf[p];
        }
    }
}

// ---------------- fine sort + rp emit: 1 block / 512-row bucket, 4 chunks ----
// R9 version; es entries KEEP the row bits ((row&511)<<18 | col) for spmmB.
__global__ __launch_bounds__(512)
void fine_kernel(const int2* __restrict__ es2, const int* __restrict__ bbase,
                 int2* __restrict__ es, int* __restrict__ rp, int n, int nnz) {
    __shared__ int2 obuf[FCAP];
    __shared__ int hist[512], scn[512], cur[128];
    int b = blockIdx.x, t = threadIdx.x;  // 512 threads
    int r0 = b << BSH;
    int s = bbase[b], e = bbase[b + 1];
    if (b == 0 && t == 0) rp[n] = nnz;

    hist[t] = 0;
    __syncthreads();
    for (int i = s + t; i < e; i += 512)
        atomicAdd(&hist[(unsigned)es2[i].x >> 18], 1);
    __syncthreads();
    scn[t] = hist[t];
    __syncthreads();
    for (int off = 1; off < 512; off <<= 1) {
        int a = (t >= off) ? scn[t - off] : 0;
        __syncthreads();
        scn[t] += a;
        __syncthreads();
    }
    {
        int ex = scn[t] - hist[t];
        int r = r0 + t;
        if (r < n) rp[r] = s + ex;
    }

    for (int c = 0; c < 4; ++c) {
        int qb = c * 128;
        int q0 = qb ? scn[qb - 1] : 0;           // excl prefix at chunk start
        int qcnt = scn[qb + 127] - q0;
        int ds = s + q0;
        bool fit = (qcnt <= FCAP);
        if (t < 128) {
            int ex = scn[qb + t] - hist[qb + t];
            cur[t] = fit ? (ex - q0) : (s + ex);  // LDS slot vs global dest
        }
        __syncthreads();
        if (fit) {
            for (int i = s + t; i < e; i += 512) {
                int2 p = es2[i];
                int rl = (unsigned)p.x >> 18;
                if ((rl >> 7) == c) {
                    int pos = atomicAdd(&cur[rl & 127], 1);
                    obuf[pos] = p;  // keep row bits
                }
            }
            __syncthreads();
            for (int p2 = t; p2 < qcnt; p2 += 512)
                es[ds + p2] = obuf[p2];
            __syncthreads();
        } else {
            // statistically-unreachable overflow: direct global scatter
            for (int i = s + t; i < e; i += 512) {
                int2 p = es2[i];
                int rl = (unsigned)p.x >> 18;
                if ((rl >> 7) == c) {
                    int pos = atomicAdd(&cur[rl & 127], 1);
                    es[pos] = p;  // keep row bits
                }
            }
            __syncthreads();
        }
    }
}

// ---------------- SpMM: 128-row LDS-accumulate blocks ----------------
// Block owns rows [r0, r0+128) and the contiguous es range [rp[r0], rp[rend]).
// 256 threads = 4 waves; per wave-iter 32 edges (8 per 16-lane quarter);
// lane's quarter-sub owns 4 dims; ds_add_f32 into acc[128][YP].

__global__ __launch_bounds__(256)
void spmmB_kernel(const u16* __restrict__ x, u16* __restrict__ y,
                  const int* __restrict__ rp, const int2* __restrict__ es, int n) {
    __shared__ float acc[128 * YP];
    int t = threadIdx.x;
    int r0 = blockIdx.x << 7;
    int rend = r0 + 128; if (rend > n) rend = n;
    int e0 = rp[r0], e1 = rp[rend];

    for (int i = t; i < 128 * YP; i += 256) acc[i] = 0.f;
    __syncthreads();

    int lane = t & 63;
    int wv   = t >> 6;
    int qt   = lane >> 4;
    int sub  = lane & 15;
    const u16* xs = x + (sub << 2);

    for (int eb = e0 + (wv << 5); eb < e1; eb += 128) {
        int base = eb + (qt << 3);
        int2 p[8]; U4 v[8]; bool m[8];
#pragma unroll
        for (int j = 0; j < 8; ++j) {
            int e = base + j;
            m[j] = (e < e1);
            int ec = m[j] ? e : (e1 - 1);
            p[j] = es[ec];
        }
#pragma unroll
        for (int j = 0; j < 8; ++j)
            v[j] = *(const U4*)(xs + ((p[j].x & 0x3FFFF) << 6));
#pragma unroll
        for (int j = 0; j < 8; ++j) {
            if (m[j]) {
                float w = __int_as_float(p[j].y);
                int rl = ((unsigned)p[j].x >> 18) & 127;
                float* a = acc + rl * YP + (sub << 2);
                atomicAdd(a + 0, w * bf2f(v[j].a));
                atomicAdd(a + 1, w * bf2f(v[j].b));
                atomicAdd(a + 2, w * bf2f(v[j].c));
                atomicAdd(a + 3, w * bf2f(v[j].d));
            }
        }
    }
    __syncthreads();

    int nr = rend - r0;
    for (int i = t; i < nr * 16; i += 256) {
        int r = i >> 4, dq = i & 15;
        const float* a = acc + r * YP + dq * 4;
        U4 o;
        o.a = f2bf(a[0]); o.b = f2bf(a[1]); o.c = f2bf(a[2]); o.d = f2bf(a[3]);
        *(U4*)(y + ((r0 + r) << 6) + (dq << 2)) = o;
    }
}

__global__ __launch_bounds__(256)
void spmmB_last_kernel(const u16* __restrict__ x2, const u16* __restrict__ x1,
                       float* __restrict__ out,
                       const int* __restrict__ rp, const int2* __restrict__ es, int n) {
    __shared__ float acc[128 * YP];
    int t = threadIdx.x;
    int r0 = blockIdx.x << 7;
    int rend = r0 + 128; if (rend > n) rend = n;
    int e0 = rp[r0], e1 = rp[rend];

    for (int i = t; i < 128 * YP; i += 256) acc[i] = 0.f;
    __syncthreads();

    int lane = t & 63;
    int wv   = t >> 6;
    int qt   = lane >> 4;
    int sub  = lane & 15;
    const u16* xs = x2 + (sub << 2);

    for (int eb = e0 + (wv << 5); eb < e1; eb += 128) {
        int base = eb + (qt << 3);
        int2 p[8]; U4 v[8]; bool m[8];
#pragma unroll
        for (int j = 0; j < 8; ++j) {
            int e = base + j;
            m[j] = (e < e1);
            int ec = m[j] ? e : (e1 - 1);
            p[j] = es[ec];
        }
#pragma unroll
        for (int j = 0; j < 8; ++j)
            v[j] = *(const U4*)(xs + ((p[j].x & 0x3FFFF) << 6));
#pragma unroll
        for (int j = 0; j < 8; ++j) {
            if (m[j]) {
                float w = __int_as_float(p[j].y);
                int rl = ((unsigned)p[j].x >> 18) & 127;
                float* a = acc + rl * YP + (sub << 2);
                atomicAdd(a + 0, w * bf2f(v[j].a));
                atomicAdd(a + 1, w * bf2f(v[j].b));
                atomicAdd(a + 2, w * bf2f(v[j].c));
                atomicAdd(a + 3, w * bf2f(v[j].d));
            }
        }
    }
    __syncthreads();

    int nr = rend - r0;
    for (int i = t; i < nr * 16; i += 256) {
        int r = i >> 4, dq = i & 15;
        int idx = ((r0 + r) << 6) + (dq << 2);
        const float* a = acc + r * YP + dq * 4;
        U4 h1v = *(const U4*)(x1 + idx);
        U4 h2v = *(const U4*)(x2 + idx);
        float h1a = bf2f(h1v.a), h1b = bf2f(h1v.b), h1c = bf2f(h1v.c), h1d = bf2f(h1v.d);
        float4 o;
        o.x = (h1a + bf2f(h2v.a) + a[0]) * (1.0f / 3.0f);
        o.y = (h1b + bf2f(h2v.b) + a[1]) * (1.0f / 3.0f);
        o.z = (h1c + bf2f(h2v.c) + a[2]) * (1.0f / 3.0f);
        o.w = (h1d + bf2f(h2v.d) + a[3]) * (1.0f / 3.0f);
        *(float4*)(out + idx) = o;
        float4 l;
        l.x = h1a; l.y = h1b; l.z = h1c; l.w = h1d;
        *(float4*)(out + (size_t)n * D + idx) = l;
    }
}

// ---------------- launch ----------------

extern "C" void kernel_launch(void* const* d_in, const int* in_sizes, int n_in,
                              void* d_out, int out_size, void* d_ws, size_t ws_size,
                              hipStream_t stream) {
    const void* ue   = d_in[0];
    const void* ie   = d_in[1];
    const int*  row  = (const int*)d_in[2];
    const int*  col  = (const int*)d_in[3];
    const void* vals = d_in[4];

    const int nu  = in_sizes[0] / D;   // 100000
    const int ni  = in_sizes[1] / D;   //  50000
    const int n   = nu + ni;           // 150000
    const int nnz = in_sizes[2];       // 4800000

    // workspace (~97 MB). es2 aliases X1+X2 (dead before spmm writes X1).
    char* ws = (char*)d_ws;
    u16*  X0     = (u16*)ws;   ws += (size_t)n * D * sizeof(u16);
    u16*  X1     = (u16*)ws;   ws += (size_t)n * D * sizeof(u16);
    u16*  X2     = (u16*)ws;   ws += (size_t)n * D * sizeof(u16);
    int2* es2    = (int2*)X1;  // nnz*8B == 2*n*D*2B exactly
    int2* es     = (int2*)ws;  ws += (size_t)nnz * sizeof(int2);
    int*  rp     = (int*)ws;   ws += (size_t)(n + 1) * sizeof(int);
    int*  bcnt   = (int*)ws;   ws += NBP * sizeof(int);
    int*  flags  = (int*)ws;   ws += 2 * sizeof(int);
    int*  bbase  = (int*)ws;   ws += (NBP + 1) * sizeof(int);
    int*  bcursor= (int*)ws;   ws += NBP * sizeof(int);

    const int tb = 256;
    const int bblocks = (n + 127) / 128;            // 1172 LDS-accum blocks
    const int cblocks = (n * D / 4 + tb - 1) / tb;
    const int NB      = (n + 511) / 512;            // 293
    const int coarseb = (nnz + TILE - 1) / TILE;    // 2344

    // zero bcnt + flags (contiguous)
    hipMemsetAsync(bcnt, 0, (NBP + 2) * sizeof(int), stream);
    detect_kernel <<<1, 64, 0, stream>>>((const u16*)ue, (const u16*)vals, flags);
    convert_kernel<<<cblocks, tb, 0, stream>>>(ue, ie, flags, X0, n * D, nu * D);
    bhist_kernel  <<<512, tb, 0, stream>>>(row, bcnt, nnz);
    bscan_kernel  <<<1, NBP, 0, stream>>>(bcnt, bbase, bcursor, NB, nnz);
    coarse_kernel <<<coarseb, tb, 0, stream>>>(row, col, vals, flags, bcursor, es2, nnz);
    fine_kernel   <<<NB, 512, 0, stream>>>(es2, bbase, es, rp, n, nnz);

    spmmB_kernel     <<<bblocks, tb, 0, stream>>>(X0, X1, rp, es, n);
    spmmB_kernel     <<<bblocks, tb, 0, stream>>>(X1, X2, rp, es, n);
    spmmB_last_kernel<<<bblocks, tb, 0, stream>>>(X2, X1, (float*)d_out, rp, es, n);
}

// Round 7
// 772.311 us; speedup vs baseline: 6.9705x; 6.9705x over previous
//
#include <hip/hip_runtime.h>
#include <hip/hip_bf16.h>

// LightGCN 3-hop GraphConv (M4_86749749444857).
// R12->R13: LDS-atomic spmmB reverted (generic-pointer shared atomicAdd
// serialized; 1.7ms/dispatch). Sort pipeline = R9 exact. SpMM is R9's
// 4-rows/wave gather, DIM-SPLIT into two independent half-chains
// (dims 0-31 | 32-63, 9.6MB arrays): y_h = A^3 x_h, so each half's 3 hops run
// back-to-back with a 9.6MB chip-wide gather footprint (was 19.2MB) to cut
// L2 capacity misses at the ~3.7TB/s L2<->L3 service ceiling. Cost: es
// streamed 6x instead of 3x. Accumulation order per dim unchanged (bit-
// identical to R9).

#define D 64
typedef unsigned short u16;

#define NBP   512    // padded bucket count (real NB = ceil(n/512) = 293)
#define BSH   9      // 512 rows/bucket
#define TILE  2048   // edges per coarse block
#define FCAP  4608   // fine LDS chunk slots (128 rows x 32 mean = 4096 + 8 sigma)

__device__ __forceinline__ float bf2f(u16 h) {
    union { unsigned int u; float f; } c;
    c.u = ((unsigned int)h) << 16;
    return c.f;
}
__device__ __forceinline__ u16 f2bf(float f) {
    union { float f; unsigned int u; } c; c.f = f;
    unsigned int r = c.u + 0x7FFFu + ((c.u >> 16) & 1u);  // RNE
    return (u16)(r >> 16);
}

struct U4 { u16 a, b, c, d; } __attribute__((aligned(8)));
struct U2 { u16 a, b; } __attribute__((aligned(4)));

// ---------------- dtype sniffing ----------------
__global__ void detect_kernel(const u16* __restrict__ emb,
                              const u16* __restrict__ vals,
                              int* __restrict__ flags) {
    int lane = threadIdx.x;  // 64 threads, 1 block
    int se = 0, sv = 0;
    for (int k = 0; k < 16; ++k) {
        int idx = (lane * 16 + k) * 2;
        u16 he = emb[idx];
        int ee = (he >> 7) & 0xFF;
        if (ee >= 100 && ee < 127) se++;
        u16 hv = vals[idx];
        int ev = (hv >> 7) & 0xFF;
        if ((hv >> 15) == 0 && ev >= 60 && ev < 123) sv++;
    }
    atomicAdd(&flags[0], se);
    atomicAdd(&flags[1], sv);
}

// ---------------- ego -> bf16 X0 (dim-split halves) ----------------
__global__ __launch_bounds__(256)
void convert_kernel(const void* __restrict__ ue, const void* __restrict__ ie,
                    const int* __restrict__ flags,
                    u16* __restrict__ xa, u16* __restrict__ xb,
                    int total, int usz) {
    int i = (blockIdx.x * blockDim.x + threadIdx.x) * 4;
    if (i >= total) return;
    const void* src = (i < usz) ? ue : ie;
    int off = (i < usz) ? i : i - usz;
    U4 o;
    if (flags[0] >= 512) {
        o = *(const U4*)((const u16*)src + off);
    } else {
        const float4 v = *(const float4*)((const float*)src + off);
        o.a = f2bf(v.x); o.b = f2bf(v.y); o.c = f2bf(v.z); o.d = f2bf(v.w);
    }
    int node = i >> 6, dim = i & 63;
    u16* dst = (dim & 32) ? xb : xa;
    *(U4*)(dst + (node << 5) + (dim & 31)) = o;
}

// ---------------- bucket histogram (LDS-aggregated) ----------------
__global__ __launch_bounds__(256)
void bhist_kernel(const int* __restrict__ row, int* __restrict__ bcnt, int nnz) {
    __shared__ int h[NBP];
    int t = threadIdx.x;
    h[t] = 0; h[t + 256] = 0;
    __syncthreads();
    for (int i = blockIdx.x * 256 + t; i < nnz; i += gridDim.x * 256)
        atomicAdd(&h[row[i] >> BSH], 1);
    __syncthreads();
    if (h[t])       atomicAdd(&bcnt[t],       h[t]);
    if (h[t + 256]) atomicAdd(&bcnt[t + 256], h[t + 256]);
}

// single block, 512 threads: exclusive scan of bucket counts
__global__ void bscan_kernel(const int* __restrict__ bcnt, int* __restrict__ bbase,
                             int* __restrict__ bcursor, int nb, int nnz) {
    __shared__ int buf[NBP];
    int t = threadIdx.x;
    int v = (t < nb) ? bcnt[t] : 0;
    buf[t] = v;
    __syncthreads();
    for (int off = 1; off < NBP; off <<= 1) {
        int y = (t >= off) ? buf[t - off] : 0;
        __syncthreads();
        buf[t] += y;
        __syncthreads();
    }
    int excl = buf[t] - v;
    bbase[t] = excl;
    bcursor[t] = excl;
    if (t == 0) bbase[nb] = nnz;
}

// ---------------- coarse sort: COO -> bucket-grouped es2 ----------------
// es2 entry: .x = (row&511)<<18 | col   .y = val bits
__global__ __launch_bounds__(256)
void coarse_kernel(const int* __restrict__ row, const int* __restrict__ col,
                   const void* __restrict__ vals, const int* __restrict__ flags,
                   int* __restrict__ bcursor, int2* __restrict__ es2, int nnz) {
    __shared__ int2 ebuf[TILE];
    __shared__ u16  slotb[TILE];
    __shared__ int  hcnt[NBP], hscn[NBP], goff[NBP];
    int t = threadIdx.x;
    int base = blockIdx.x * TILE;
    int tcnt = nnz - base; if (tcnt > TILE) tcnt = TILE;
    bool vbf = (flags[1] >= 512);

    hcnt[t] = 0; hcnt[t + 256] = 0;
    __syncthreads();

    int eb[8], er[8], ep[8], ev[8];
#pragma unroll
    for (int k = 0; k < 8; ++k) {
        int i = base + k * 256 + t;
        eb[k] = -1;
        if (k * 256 + t < tcnt) {
            int r = row[i];
            int c = col[i];
            float v = vbf ? bf2f(((const u16*)vals)[i]) : ((const float*)vals)[i];
            eb[k] = r >> BSH;
            ep[k] = ((r & 511) << 18) | c;
            ev[k] = __float_as_int(v);
            er[k] = atomicAdd(&hcnt[eb[k]], 1);
        }
    }
    __syncthreads();
    hscn[t] = hcnt[t]; hscn[t + 256] = hcnt[t + 256];
    __syncthreads();
    for (int off = 1; off < NBP; off <<= 1) {
        int a0 = (t >= off) ? hscn[t - off] : 0;
        int a1 = (t + 256 >= off) ? hscn[t + 256 - off] : 0;
        __syncthreads();
        hscn[t] += a0; hscn[t + 256] += a1;
        __syncthreads();
    }
#pragma unroll
    for (int k = 0; k < 8; ++k) {
        if (eb[k] >= 0) {
            int slot = hscn[eb[k]] - hcnt[eb[k]] + er[k];
            ebuf[slot] = make_int2(ep[k], ev[k]);
            slotb[slot] = (u16)eb[k];
        }
    }
    __syncthreads();
    if (hcnt[t] > 0)       goff[t]       = atomicAdd(&bcursor[t],       hcnt[t]);
    if (hcnt[t + 256] > 0) goff[t + 256] = atomicAdd(&bcursor[t + 256], hcnt[t + 256]);
    __syncthreads();
#pragma unroll
    for (int k = 0; k < 8; ++k) {
        int p = k * 256 + t;
        if (p < tcnt) {
            int b = slotb[p];
            int dest = goff[b] + (p - (hscn[b] - hcnt[b]));
            es2[dest] = ebuf[p];
        }
    }
}

// ---------------- fine sort + rp emit: 1 block / 512-row bucket, 4 chunks ----
// R9 version: stage chunk to obuf at sorted positions, stream coalesced.
__global__ __launch_bounds__(512)
void fine_kernel(const int2* __restrict__ es2, const int* __restrict__ bbase,
                 int2* __restrict__ es, int* __restrict__ rp, int n, int nnz) {
    __shared__ int2 obuf[FCAP];
    __shared__ int hist[512], scn[512], cur[128];
    int b = blockIdx.x, t = threadIdx.x;  // 512 threads
    int r0 = b << BSH;
    int s = bbase[b], e = bbase[b + 1];
    if (b == 0 && t == 0) rp[n] = nnz;

    hist[t] = 0;
    __syncthreads();
    for (int i = s + t; i < e; i += 512)
        atomicAdd(&hist[(unsigned)es2[i].x >> 18], 1);
    __syncthreads();
    scn[t] = hist[t];
    __syncthreads();
    for (int off = 1; off < 512; off <<= 1) {
        int a = (t >= off) ? scn[t - off] : 0;
        __syncthreads();
        scn[t] += a;
        __syncthreads();
    }
    {
        int ex = scn[t] - hist[t];
        int r = r0 + t;
        if (r < n) rp[r] = s + ex;
    }

    for (int c = 0; c < 4; ++c) {
        int qb = c * 128;
        int q0 = qb ? scn[qb - 1] : 0;           // excl prefix at chunk start
        int qcnt = scn[qb + 127] - q0;
        int ds = s + q0;
        bool fit = (qcnt <= FCAP);
        if (t < 128) {
            int ex = scn[qb + t] - hist[qb + t];
            cur[t] = fit ? (ex - q0) : (s + ex);  // LDS slot vs global dest
        }
        __syncthreads();
        if (fit) {
            for (int i = s + t; i < e; i += 512) {
                int2 p = es2[i];
                int rl = (unsigned)p.x >> 18;
                if ((rl >> 7) == c) {
                    int pos = atomicAdd(&cur[rl & 127], 1);
                    obuf[pos] = make_int2(p.x & 0x3FFFF, p.y);
                }
            }
            __syncthreads();
            for (int p2 = t; p2 < qcnt; p2 += 512)
                es[ds + p2] = obuf[p2];
            __syncthreads();
        } else {
            // statistically-unreachable overflow: direct global scatter
            for (int i = s + t; i < e; i += 512) {
                int2 p = es2[i];
                int rl = (unsigned)p.x >> 18;
                if ((rl >> 7) == c) {
                    int pos = atomicAdd(&cur[rl & 127], 1);
                    es[pos] = make_int2(p.x & 0x3FFFF, p.y);
                }
            }
            __syncthreads();
        }
    }
}

// ---------------- SpMM half: 4 rows/wave, 16 lanes/row, ushort2 gather ------
// Half-array rows are 32 elems (64B). Lane l: quarter qt = l>>4 owns row
// (wid*4 + qt); sub = l&15 owns dims 2*sub, 2*sub+1 of the half.

__global__ __launch_bounds__(256)
void spmmh_kernel(const u16* __restrict__ x, u16* __restrict__ y,
                  const int* __restrict__ rp, const int2* __restrict__ es, int n) {
    int wid  = (blockIdx.x * blockDim.x + threadIdx.x) >> 6;
    int lane = threadIdx.x & 63;
    int qt   = lane >> 4;
    int sub  = lane & 15;
    int r    = (wid << 2) + qt;
    int e = 0, e1 = 0;
    if (r < n) { e = rp[r]; e1 = rp[r + 1]; }
    const u16* xs = x + (sub << 1);

    float a0 = 0.f, a1 = 0.f, b0 = 0.f, b1 = 0.f;

    for (; e + 8 <= e1; e += 8) {
        int2 p0 = es[e],     p1 = es[e + 1], p2 = es[e + 2], p3 = es[e + 3];
        int2 p4 = es[e + 4], p5 = es[e + 5], p6 = es[e + 6], p7 = es[e + 7];
        U2 v0 = *(const U2*)(xs + (p0.x << 5));
        U2 v1 = *(const U2*)(xs + (p1.x << 5));
        U2 v2 = *(const U2*)(xs + (p2.x << 5));
        U2 v3 = *(const U2*)(xs + (p3.x << 5));
        U2 v4 = *(const U2*)(xs + (p4.x << 5));
        U2 v5 = *(const U2*)(xs + (p5.x << 5));
        U2 v6 = *(const U2*)(xs + (p6.x << 5));
        U2 v7 = *(const U2*)(xs + (p7.x << 5));
        float w0 = __int_as_float(p0.y), w1 = __int_as_float(p1.y);
        float w2 = __int_as_float(p2.y), w3 = __int_as_float(p3.y);
        float w4 = __int_as_float(p4.y), w5 = __int_as_float(p5.y);
        float w6 = __int_as_float(p6.y), w7 = __int_as_float(p7.y);
        a0 += w0 * bf2f(v0.a); a1 += w0 * bf2f(v0.b);
        b0 += w1 * bf2f(v1.a); b1 += w1 * bf2f(v1.b);
        a0 += w2 * bf2f(v2.a); a1 += w2 * bf2f(v2.b);
        b0 += w3 * bf2f(v3.a); b1 += w3 * bf2f(v3.b);
        a0 += w4 * bf2f(v4.a); a1 += w4 * bf2f(v4.b);
        b0 += w5 * bf2f(v5.a); b1 += w5 * bf2f(v5.b);
        a0 += w6 * bf2f(v6.a); a1 += w6 * bf2f(v6.b);
        b0 += w7 * bf2f(v7.a); b1 += w7 * bf2f(v7.b);
    }
    for (; e < e1; ++e) {
        int2 p = es[e];
        U2 v = *(const U2*)(xs + (p.x << 5));
        float w = __int_as_float(p.y);
        a0 += w * bf2f(v.a); a1 += w * bf2f(v.b);
    }
    if (r < n) {
        U2 o;
        o.a = f2bf(a0 + b0); o.b = f2bf(a1 + b1);
        *(U2*)(y + (r << 5) + (sub << 1)) = o;
    }
}

__global__ __launch_bounds__(256)
void spmmh_last_kernel(const u16* __restrict__ x2, const u16* __restrict__ x1,
                       float* __restrict__ out,
                       const int* __restrict__ rp, const int2* __restrict__ es,
                       int n, int hoff) {
    int wid  = (blockIdx.x * blockDim.x + threadIdx.x) >> 6;
    int lane = threadIdx.x & 63;
    int qt   = lane >> 4;
    int sub  = lane & 15;
    int r    = (wid << 2) + qt;
    int e = 0, e1 = 0;
    if (r < n) { e = rp[r]; e1 = rp[r + 1]; }
    const u16* xs = x2 + (sub << 1);

    float a0 = 0.f, a1 = 0.f, b0 = 0.f, b1 = 0.f;

    for (; e + 8 <= e1; e += 8) {
        int2 p0 = es[e],     p1 = es[e + 1], p2 = es[e + 2], p3 = es[e + 3];
        int2 p4 = es[e + 4], p5 = es[e + 5], p6 = es[e + 6], p7 = es[e + 7];
        U2 v0 = *(const U2*)(xs + (p0.x << 5));
        U2 v1 = *(const U2*)(xs + (p1.x << 5));
        U2 v2 = *(const U2*)(xs + (p2.x << 5));
        U2 v3 = *(const U2*)(xs + (p3.x << 5));
        U2 v4 = *(const U2*)(xs + (p4.x << 5));
        U2 v5 = *(const U2*)(xs + (p5.x << 5));
        U2 v6 = *(const U2*)(xs + (p6.x << 5));
        U2 v7 = *(const U2*)(xs + (p7.x << 5));
        float w0 = __int_as_float(p0.y), w1 = __int_as_float(p1.y);
        float w2 = __int_as_float(p2.y), w3 = __int_as_float(p3.y);
        float w4 = __int_as_float(p4.y), w5 = __int_as_float(p5.y);
        float w6 = __int_as_float(p6.y), w7 = __int_as_float(p7.y);
        a0 += w0 * bf2f(v0.a); a1 += w0 * bf2f(v0.b);
        b0 += w1 * bf2f(v1.a); b1 += w1 * bf2f(v1.b);
        a0 += w2 * bf2f(v2.a); a1 += w2 * bf2f(v2.b);
        b0 += w3 * bf2f(v3.a); b1 += w3 * bf2f(v3.b);
        a0 += w4 * bf2f(v4.a); a1 += w4 * bf2f(v4.b);
        b0 += w5 * bf2f(v5.a); b1 += w5 * bf2f(v5.b);
        a0 += w6 * bf2f(v6.a); a1 += w6 * bf2f(v6.b);
        b0 += w7 * bf2f(v7.a); b1 += w7 * bf2f(v7.b);
    }
    for (; e < e1; ++e) {
        int2 p = es[e];
        U2 v = *(const U2*)(xs + (p.x << 5));
        float w = __int_as_float(p.y);
        a0 += w * bf2f(v.a); a1 += w * bf2f(v.b);
    }
    if (r < n) {
        int hidx = (r << 5) + (sub << 1);
        U2 h1v = *(const U2*)(x1 + hidx);
        U2 h2v = *(const U2*)(x2 + hidx);
        float h1a = bf2f(h1v.a), h1b = bf2f(h1v.b);
        int oidx = (r << 6) + hoff + (sub << 1);
        float2 o;
        o.x = (h1a + bf2f(h2v.a) + (a0 + b0)) * (1.0f / 3.0f);
        o.y = (h1b + bf2f(h2v.b) + (a1 + b1)) * (1.0f / 3.0f);
        *(float2*)(out + oidx) = o;
        float2 l;
        l.x = h1a; l.y = h1b;
        *(float2*)(out + (size_t)n * D + oidx) = l;
    }
}

// ---------------- launch ----------------

extern "C" void kernel_launch(void* const* d_in, const int* in_sizes, int n_in,
                              void* d_out, int out_size, void* d_ws, size_t ws_size,
                              hipStream_t stream) {
    const void* ue   = d_in[0];
    const void* ie   = d_in[1];
    const int*  row  = (const int*)d_in[2];
    const int*  col  = (const int*)d_in[3];
    const void* vals = d_in[4];

    const int nu  = in_sizes[0] / D;   // 100000
    const int ni  = in_sizes[1] / D;   //  50000
    const int n   = nu + ni;           // 150000
    const int nnz = in_sizes[2];       // 4800000

    // workspace (~97 MB). es2 aliases X1a..X2b (dead before spmm writes X1a).
    const size_t hsz = (size_t)n * 32 * sizeof(u16);  // 9.6 MB per half-array
    char* ws = (char*)d_ws;
    u16*  X0a    = (u16*)ws;   ws += hsz;
    u16*  X0b    = (u16*)ws;   ws += hsz;
    u16*  X1a    = (u16*)ws;   ws += hsz;
    u16*  X2a    = (u16*)ws;   ws += hsz;
    u16*  X1b    = (u16*)ws;   ws += hsz;
    u16*  X2b    = (u16*)ws;   ws += hsz;
    int2* es2    = (int2*)X1a; // nnz*8B == 4*hsz exactly
    int2* es     = (int2*)ws;  ws += (size_t)nnz * sizeof(int2);
    int*  rp     = (int*)ws;   ws += (size_t)(n + 1) * sizeof(int);
    int*  bcnt   = (int*)ws;   ws += NBP * sizeof(int);
    int*  flags  = (int*)ws;   ws += 2 * sizeof(int);
    int*  bbase  = (int*)ws;   ws += (NBP + 1) * sizeof(int);
    int*  bcursor= (int*)ws;   ws += NBP * sizeof(int);

    const int tb = 256;
    const int rblocks = (n + 15) / 16;             // 4 rows/wave, 4 waves/block
    const int cblocks = (n * D / 4 + tb - 1) / tb;
    const int NB      = (n + 511) / 512;            // 293
    const int coarseb = (nnz + TILE - 1) / TILE;    // 2344

    // zero bcnt + flags (contiguous)
    hipMemsetAsync(bcnt, 0, (NBP + 2) * sizeof(int), stream);
    detect_kernel <<<1, 64, 0, stream>>>((const u16*)ue, (const u16*)vals, flags);
    convert_kernel<<<cblocks, tb, 0, stream>>>(ue, ie, flags, X0a, X0b, n * D, nu * D);
    bhist_kernel  <<<512, tb, 0, stream>>>(row, bcnt, nnz);
    bscan_kernel  <<<1, NBP, 0, stream>>>(bcnt, bbase, bcursor, NB, nnz);
    coarse_kernel <<<coarseb, tb, 0, stream>>>(row, col, vals, flags, bcursor, es2, nnz);
    fine_kernel   <<<NB, 512, 0, stream>>>(es2, bbase, es, rp, n, nnz);

    // half A (dims 0-31): 3-hop chain with 9.6MB gather footprint
    spmmh_kernel     <<<rblocks, tb, 0, stream>>>(X0a, X1a, rp, es, n);
    spmmh_kernel     <<<rblocks, tb, 0, stream>>>(X1a, X2a, rp, es, n);
    spmmh_last_kernel<<<rblocks, tb, 0, stream>>>(X2a, X1a, (float*)d_out, rp, es, n, 0);
    // half B (dims 32-63)
    spmmh_kernel     <<<rblocks, tb, 0, stream>>>(X0b, X1b, rp, es, n);
    spmmh_kernel     <<<rblocks, tb, 0, stream>>>(X1b, X2b, rp, es, n);
    spmmh_last_kernel<<<rblocks, tb, 0, stream>>>(X2b, X1b, (float*)d_out, rp, es, n, 32);
}

// Round 8
// 611.222 us; speedup vs baseline: 8.8076x; 1.2636x over previous
//
#include <hip/hip_runtime.h>
#include <hip/hip_bf16.h>

// LightGCN 3-hop GraphConv (M4_86749749444857).
// R14 = exact revert to R9 (609us best). Session evidence that this is the
// plateau: spmm gather is service-bound at ~3.7TB/s TCC rate (R9 vs R10: 2x
// MLP, same rate); temporal clustering fails (R11 band-sweep desyncs by row
// degree); footprint halving fails (R13 dim-split: es-stream tax cancels the
// capacity win); LDS-atomic accumulate serializes (R12). Measured 296MB
// fetch/hop vs ~192MB compulsory floor (8-XCD x replication + es stream).
// Sort pipeline: coarse ~92us (scan/barrier-bound), fine ~75us (1 HBM pass +
// 4 L2-hot chunk passes), both with streaming-coalesced HBM writes.

#define D 64
typedef unsigned short u16;

#define NBP   512    // padded bucket count (real NB = ceil(n/512) = 293)
#define BSH   9      // 512 rows/bucket
#define TILE  2048   // edges per coarse block
#define FCAP  4608   // fine LDS chunk slots (128 rows x 32 mean = 4096 + 8 sigma)

__device__ __forceinline__ float bf2f(u16 h) {
    union { unsigned int u; float f; } c;
    c.u = ((unsigned int)h) << 16;
    return c.f;
}
__device__ __forceinline__ u16 f2bf(float f) {
    union { float f; unsigned int u; } c; c.f = f;
    unsigned int r = c.u + 0x7FFFu + ((c.u >> 16) & 1u);  // RNE
    return (u16)(r >> 16);
}

struct U4 { u16 a, b, c, d; } __attribute__((aligned(8)));

// ---------------- dtype sniffing ----------------
__global__ void detect_kernel(const u16* __restrict__ emb,
                              const u16* __restrict__ vals,
                              int* __restrict__ flags) {
    int lane = threadIdx.x;  // 64 threads, 1 block
    int se = 0, sv = 0;
    for (int k = 0; k < 16; ++k) {
        int idx = (lane * 16 + k) * 2;
        u16 he = emb[idx];
        int ee = (he >> 7) & 0xFF;
        if (ee >= 100 && ee < 127) se++;
        u16 hv = vals[idx];
        int ev = (hv >> 7) & 0xFF;
        if ((hv >> 15) == 0 && ev >= 60 && ev < 123) sv++;
    }
    atomicAdd(&flags[0], se);
    atomicAdd(&flags[1], sv);
}

// ---------------- ego -> bf16 X0 ----------------
__global__ __launch_bounds__(256)
void convert_kernel(const void* __restrict__ ue, const void* __restrict__ ie,
                    const int* __restrict__ flags, u16* __restrict__ x0,
                    int total, int usz) {
    int i = (blockIdx.x * blockDim.x + threadIdx.x) * 4;
    if (i >= total) return;
    const void* src = (i < usz) ? ue : ie;
    int off = (i < usz) ? i : i - usz;
    U4 o;
    if (flags[0] >= 512) {
        o = *(const U4*)((const u16*)src + off);
    } else {
        const float4 v = *(const float4*)((const float*)src + off);
        o.a = f2bf(v.x); o.b = f2bf(v.y); o.c = f2bf(v.z); o.d = f2bf(v.w);
    }
    *(U4*)(x0 + i) = o;
}

// ---------------- bucket histogram (LDS-aggregated) ----------------
__global__ __launch_bounds__(256)
void bhist_kernel(const int* __restrict__ row, int* __restrict__ bcnt, int nnz) {
    __shared__ int h[NBP];
    int t = threadIdx.x;
    h[t] = 0; h[t + 256] = 0;
    __syncthreads();
    for (int i = blockIdx.x * 256 + t; i < nnz; i += gridDim.x * 256)
        atomicAdd(&h[row[i] >> BSH], 1);
    __syncthreads();
    if (h[t])       atomicAdd(&bcnt[t],       h[t]);
    if (h[t + 256]) atomicAdd(&bcnt[t + 256], h[t + 256]);
}

// single block, 512 threads: exclusive scan of bucket counts
__global__ void bscan_kernel(const int* __restrict__ bcnt, int* __restrict__ bbase,
                             int* __restrict__ bcursor, int nb, int nnz) {
    __shared__ int buf[NBP];
    int t = threadIdx.x;
    int v = (t < nb) ? bcnt[t] : 0;
    buf[t] = v;
    __syncthreads();
    for (int off = 1; off < NBP; off <<= 1) {
        int y = (t >= off) ? buf[t - off] : 0;
        __syncthreads();
        buf[t] += y;
        __syncthreads();
    }
    int excl = buf[t] - v;
    bbase[t] = excl;
    bcursor[t] = excl;
    if (t == 0) bbase[nb] = nnz;
}

// ---------------- coarse sort: COO -> bucket-grouped es2 ----------------
// es2 entry: .x = (row&511)<<18 | col   .y = val bits
__global__ __launch_bounds__(256)
void coarse_kernel(const int* __restrict__ row, const int* __restrict__ col,
                   const void* __restrict__ vals, const int* __restrict__ flags,
                   int* __restrict__ bcursor, int2* __restrict__ es2, int nnz) {
    __shared__ int2 ebuf[TILE];
    __shared__ u16  slotb[TILE];
    __shared__ int  hcnt[NBP], hscn[NBP], goff[NBP];
    int t = threadIdx.x;
    int base = blockIdx.x * TILE;
    int tcnt = nnz - base; if (tcnt > TILE) tcnt = TILE;
    bool vbf = (flags[1] >= 512);

    hcnt[t] = 0; hcnt[t + 256] = 0;
    __syncthreads();

    int eb[8], er[8], ep[8], ev[8];
#pragma unroll
    for (int k = 0; k < 8; ++k) {
        int i = base + k * 256 + t;
        eb[k] = -1;
        if (k * 256 + t < tcnt) {
            int r = row[i];
            int c = col[i];
            float v = vbf ? bf2f(((const u16*)vals)[i]) : ((const float*)vals)[i];
            eb[k] = r >> BSH;
            ep[k] = ((r & 511) << 18) | c;
            ev[k] = __float_as_int(v);
            er[k] = atomicAdd(&hcnt[eb[k]], 1);
        }
    }
    __syncthreads();
    hscn[t] = hcnt[t]; hscn[t + 256] = hcnt[t + 256];
    __syncthreads();
    for (int off = 1; off < NBP; off <<= 1) {
        int a0 = (t >= off) ? hscn[t - off] : 0;
        int a1 = (t + 256 >= off) ? hscn[t + 256 - off] : 0;
        __syncthreads();
        hscn[t] += a0; hscn[t + 256] += a1;
        __syncthreads();
    }
#pragma unroll
    for (int k = 0; k < 8; ++k) {
        if (eb[k] >= 0) {
            int slot = hscn[eb[k]] - hcnt[eb[k]] + er[k];
            ebuf[slot] = make_int2(ep[k], ev[k]);
            slotb[slot] = (u16)eb[k];
        }
    }
    __syncthreads();
    if (hcnt[t] > 0)       goff[t]       = atomicAdd(&bcursor[t],       hcnt[t]);
    if (hcnt[t + 256] > 0) goff[t + 256] = atomicAdd(&bcursor[t + 256], hcnt[t + 256]);
    __syncthreads();
#pragma unroll
    for (int k = 0; k < 8; ++k) {
        int p = k * 256 + t;
        if (p < tcnt) {
            int b = slotb[p];
            int dest = goff[b] + (p - (hscn[b] - hcnt[b]));
            es2[dest] = ebuf[p];
        }
    }
}

// ---------------- fine sort + rp emit: 1 block / 512-row bucket, 4 chunks ----
// Pass 1 (HBM): hist[512]. Scan once. Then per 128-row chunk: re-scan bucket
// (L2-hot), LDS-scatter chunk edges into obuf at sorted positions, stream
// obuf -> es coalesced. No scattered global writes.
__global__ __launch_bounds__(512)
void fine_kernel(const int2* __restrict__ es2, const int* __restrict__ bbase,
                 int2* __restrict__ es, int* __restrict__ rp, int n, int nnz) {
    __shared__ int2 obuf[FCAP];
    __shared__ int hist[512], scn[512], cur[128];
    int b = blockIdx.x, t = threadIdx.x;  // 512 threads
    int r0 = b << BSH;
    int s = bbase[b], e = bbase[b + 1];
    if (b == 0 && t == 0) rp[n] = nnz;

    hist[t] = 0;
    __syncthreads();
    for (int i = s + t; i < e; i += 512)
        atomicAdd(&hist[(unsigned)es2[i].x >> 18], 1);
    __syncthreads();
    scn[t] = hist[t];
    __syncthreads();
    for (int off = 1; off < 512; off <<= 1) {
        int a = (t >= off) ? scn[t - off] : 0;
        __syncthreads();
        scn[t] += a;
        __syncthreads();
    }
    {
        int ex = scn[t] - hist[t];
        int r = r0 + t;
        if (r < n) rp[r] = s + ex;
    }

    for (int c = 0; c < 4; ++c) {
        int qb = c * 128;
        int q0 = qb ? scn[qb - 1] : 0;           // excl prefix at chunk start
        int qcnt = scn[qb + 127] - q0;
        int ds = s + q0;
        bool fit = (qcnt <= FCAP);
        if (t < 128) {
            int ex = scn[qb + t] - hist[qb + t];
            cur[t] = fit ? (ex - q0) : (s + ex);  // LDS slot vs global dest
        }
        __syncthreads();
        if (fit) {
            for (int i = s + t; i < e; i += 512) {
                int2 p = es2[i];
                int rl = (unsigned)p.x >> 18;
                if ((rl >> 7) == c) {
                    int pos = atomicAdd(&cur[rl & 127], 1);
                    obuf[pos] = make_int2(p.x & 0x3FFFF, p.y);
                }
            }
            __syncthreads();
            for (int p2 = t; p2 < qcnt; p2 += 512)
                es[ds + p2] = obuf[p2];
            __syncthreads();
        } else {
            // statistically-unreachable overflow: direct global scatter
            for (int i = s + t; i < e; i += 512) {
                int2 p = es2[i];
                int rl = (unsigned)p.x >> 18;
                if ((rl >> 7) == c) {
                    int pos = atomicAdd(&cur[rl & 127], 1);
                    es[pos] = make_int2(p.x & 0x3FFFF, p.y);
                }
            }
            __syncthreads();
        }
    }
}

// ---------------- SpMM: 4 rows/wave, 16 lanes/row, ushort4 gather ----------------
// Lane l: quarter qt = l>>4 owns row (wid*4 + qt); sub = l&15 owns dims 4*sub..4*sub+3.

__global__ __launch_bounds__(256)
void spmm_kernel(const u16* __restrict__ x, u16* __restrict__ y,
                 const int* __restrict__ rp, const int2* __restrict__ es, int n) {
    int wid  = (blockIdx.x * blockDim.x + threadIdx.x) >> 6;
    int lane = threadIdx.x & 63;
    int qt   = lane >> 4;
    int sub  = lane & 15;
    int r    = (wid << 2) + qt;
    int e = 0, e1 = 0;
    if (r < n) { e = rp[r]; e1 = rp[r + 1]; }
    const u16* xs = x + (sub << 2);

    float a0 = 0.f, a1 = 0.f, a2 = 0.f, a3 = 0.f;
    float b0 = 0.f, b1 = 0.f, b2 = 0.f, b3 = 0.f;

    for (; e + 8 <= e1; e += 8) {
        int2 p0 = es[e],     p1 = es[e + 1], p2 = es[e + 2], p3 = es[e + 3];
        int2 p4 = es[e + 4], p5 = es[e + 5], p6 = es[e + 6], p7 = es[e + 7];
        U4 v0 = *(const U4*)(xs + (p0.x << 6));
        U4 v1 = *(const U4*)(xs + (p1.x << 6));
        U4 v2 = *(const U4*)(xs + (p2.x << 6));
        U4 v3 = *(const U4*)(xs + (p3.x << 6));
        U4 v4 = *(const U4*)(xs + (p4.x << 6));
        U4 v5 = *(const U4*)(xs + (p5.x << 6));
        U4 v6 = *(const U4*)(xs + (p6.x << 6));
        U4 v7 = *(const U4*)(xs + (p7.x << 6));
        float w0 = __int_as_float(p0.y), w1 = __int_as_float(p1.y);
        float w2 = __int_as_float(p2.y), w3 = __int_as_float(p3.y);
        float w4 = __int_as_float(p4.y), w5 = __int_as_float(p5.y);
        float w6 = __int_as_float(p6.y), w7 = __int_as_float(p7.y);
        a0 += w0 * bf2f(v0.a); a1 += w0 * bf2f(v0.b); a2 += w0 * bf2f(v0.c); a3 += w0 * bf2f(v0.d);
        b0 += w1 * bf2f(v1.a); b1 += w1 * bf2f(v1.b); b2 += w1 * bf2f(v1.c); b3 += w1 * bf2f(v1.d);
        a0 += w2 * bf2f(v2.a); a1 += w2 * bf2f(v2.b); a2 += w2 * bf2f(v2.c); a3 += w2 * bf2f(v2.d);
        b0 += w3 * bf2f(v3.a); b1 += w3 * bf2f(v3.b); b2 += w3 * bf2f(v3.c); b3 += w3 * bf2f(v3.d);
        a0 += w4 * bf2f(v4.a); a1 += w4 * bf2f(v4.b); a2 += w4 * bf2f(v4.c); a3 += w4 * bf2f(v4.d);
        b0 += w5 * bf2f(v5.a); b1 += w5 * bf2f(v5.b); b2 += w5 * bf2f(v5.c); b3 += w5 * bf2f(v5.d);
        a0 += w6 * bf2f(v6.a); a1 += w6 * bf2f(v6.b); a2 += w6 * bf2f(v6.c); a3 += w6 * bf2f(v6.d);
        b0 += w7 * bf2f(v7.a); b1 += w7 * bf2f(v7.b); b2 += w7 * bf2f(v7.c); b3 += w7 * bf2f(v7.d);
    }
    for (; e < e1; ++e) {
        int2 p = es[e];
        U4 v = *(const U4*)(xs + (p.x << 6));
        float w = __int_as_float(p.y);
        a0 += w * bf2f(v.a); a1 += w * bf2f(v.b); a2 += w * bf2f(v.c); a3 += w * bf2f(v.d);
    }
    if (r < n) {
        U4 o;
        o.a = f2bf(a0 + b0); o.b = f2bf(a1 + b1);
        o.c = f2bf(a2 + b2); o.d = f2bf(a3 + b3);
        *(U4*)(y + (r << 6) + (sub << 2)) = o;
    }
}

__global__ __launch_bounds__(256)
void spmm_last_kernel(const u16* __restrict__ x2, const u16* __restrict__ x1,
                      float* __restrict__ out,
                      const int* __restrict__ rp, const int2* __restrict__ es, int n) {
    int wid  = (blockIdx.x * blockDim.x + threadIdx.x) >> 6;
    int lane = threadIdx.x & 63;
    int qt   = lane >> 4;
    int sub  = lane & 15;
    int r    = (wid << 2) + qt;
    int e = 0, e1 = 0;
    if (r < n) { e = rp[r]; e1 = rp[r + 1]; }
    const u16* xs = x2 + (sub << 2);

    float a0 = 0.f, a1 = 0.f, a2 = 0.f, a3 = 0.f;
    float b0 = 0.f, b1 = 0.f, b2 = 0.f, b3 = 0.f;

    for (; e + 8 <= e1; e += 8) {
        int2 p0 = es[e],     p1 = es[e + 1], p2 = es[e + 2], p3 = es[e + 3];
        int2 p4 = es[e + 4], p5 = es[e + 5], p6 = es[e + 6], p7 = es[e + 7];
        U4 v0 = *(const U4*)(xs + (p0.x << 6));
        U4 v1 = *(const U4*)(xs + (p1.x << 6));
        U4 v2 = *(const U4*)(xs + (p2.x << 6));
        U4 v3 = *(const U4*)(xs + (p3.x << 6));
        U4 v4 = *(const U4*)(xs + (p4.x << 6));
        U4 v5 = *(const U4*)(xs + (p5.x << 6));
        U4 v6 = *(const U4*)(xs + (p6.x << 6));
        U4 v7 = *(const U4*)(xs + (p7.x << 6));
        float w0 = __int_as_float(p0.y), w1 = __int_as_float(p1.y);
        float w2 = __int_as_float(p2.y), w3 = __int_as_float(p3.y);
        float w4 = __int_as_float(p4.y), w5 = __int_as_float(p5.y);
        float w6 = __int_as_float(p6.y), w7 = __int_as_float(p7.y);
        a0 += w0 * bf2f(v0.a); a1 += w0 * bf2f(v0.b); a2 += w0 * bf2f(v0.c); a3 += w0 * bf2f(v0.d);
        b0 += w1 * bf2f(v1.a); b1 += w1 * bf2f(v1.b); b2 += w1 * bf2f(v1.c); b3 += w1 * bf2f(v1.d);
        a0 += w2 * bf2f(v2.a); a1 += w2 * bf2f(v2.b); a2 += w2 * bf2f(v2.c); a3 += w2 * bf2f(v2.d);
        b0 += w3 * bf2f(v3.a); b1 += w3 * bf2f(v3.b); b2 += w3 * bf2f(v3.c); b3 += w3 * bf2f(v3.d);
        a0 += w4 * bf2f(v4.a); a1 += w4 * bf2f(v4.b); a2 += w4 * bf2f(v4.c); a3 += w4 * bf2f(v4.d);
        b0 += w5 * bf2f(v5.a); b1 += w5 * bf2f(v5.b); b2 += w5 * bf2f(v5.c); b3 += w5 * bf2f(v5.d);
        a0 += w6 * bf2f(v6.a); a1 += w6 * bf2f(v6.b); a2 += w6 * bf2f(v6.c); a3 += w6 * bf2f(v6.d);
        b0 += w7 * bf2f(v7.a); b1 += w7 * bf2f(v7.b); b2 += w7 * bf2f(v7.c); b3 += w7 * bf2f(v7.d);
    }
    for (; e < e1; ++e) {
        int2 p = es[e];
        U4 v = *(const U4*)(xs + (p.x << 6));
        float w = __int_as_float(p.y);
        a0 += w * bf2f(v.a); a1 += w * bf2f(v.b); a2 += w * bf2f(v.c); a3 += w * bf2f(v.d);
    }
    if (r < n) {
        int idx = (r << 6) + (sub << 2);
        U4 h1v = *(const U4*)(x1 + idx);
        U4 h2v = *(const U4*)(x2 + idx);
        float h1a = bf2f(h1v.a), h1b = bf2f(h1v.b), h1c = bf2f(h1v.c), h1d = bf2f(h1v.d);
        float h2a = bf2f(h2v.a), h2b = bf2f(h2v.b), h2c = bf2f(h2v.c), h2d = bf2f(h2v.d);
        float4 o;
        o.x = (h1a + h2a + (a0 + b0)) * (1.0f / 3.0f);
        o.y = (h1b + h2b + (a1 + b1)) * (1.0f / 3.0f);
        o.z = (h1c + h2c + (a2 + b2)) * (1.0f / 3.0f);
        o.w = (h1d + h2d + (a3 + b3)) * (1.0f / 3.0f);
        *(float4*)(out + idx) = o;
        float4 l;
        l.x = h1a; l.y = h1b; l.z = h1c; l.w = h1d;
        *(float4*)(out + (size_t)n * D + idx) = l;
    }
}

// ---------------- launch ----------------

extern "C" void kernel_launch(void* const* d_in, const int* in_sizes, int n_in,
                              void* d_out, int out_size, void* d_ws, size_t ws_size,
                              hipStream_t stream) {
    const void* ue   = d_in[0];
    const void* ie   = d_in[1];
    const int*  row  = (const int*)d_in[2];
    const int*  col  = (const int*)d_in[3];
    const void* vals = d_in[4];

    const int nu  = in_sizes[0] / D;   // 100000
    const int ni  = in_sizes[1] / D;   //  50000
    const int n   = nu + ni;           // 150000
    const int nnz = in_sizes[2];       // 4800000

    // workspace (~97 MB). es2 aliases X1+X2 (dead before spmm writes X1).
    char* ws = (char*)d_ws;
    u16*  X0     = (u16*)ws;   ws += (size_t)n * D * sizeof(u16);
    u16*  X1     = (u16*)ws;   ws += (size_t)n * D * sizeof(u16);
    u16*  X2     = (u16*)ws;   ws += (size_t)n * D * sizeof(u16);
    int2* es2    = (int2*)X1;  // nnz*8B == 2*n*D*2B exactly
    int2* es     = (int2*)ws;  ws += (size_t)nnz * sizeof(int2);
    int*  rp     = (int*)ws;   ws += (size_t)(n + 1) * sizeof(int);
    int*  bcnt   = (int*)ws;   ws += NBP * sizeof(int);
    int*  flags  = (int*)ws;   ws += 2 * sizeof(int);
    int*  bbase  = (int*)ws;   ws += (NBP + 1) * sizeof(int);
    int*  bcursor= (int*)ws;   ws += NBP * sizeof(int);

    const int tb = 256;
    const int rblocks = (n + 15) / 16;             // 4 rows/wave, 4 waves/block
    const int cblocks = (n * D / 4 + tb - 1) / tb;
    const int NB      = (n + 511) / 512;            // 293
    const int coarseb = (nnz + TILE - 1) / TILE;    // 2344

    // zero bcnt + flags (contiguous)
    hipMemsetAsync(bcnt, 0, (NBP + 2) * sizeof(int), stream);
    detect_kernel <<<1, 64, 0, stream>>>((const u16*)ue, (const u16*)vals, flags);
    convert_kernel<<<cblocks, tb, 0, stream>>>(ue, ie, flags, X0, n * D, nu * D);
    bhist_kernel  <<<512, tb, 0, stream>>>(row, bcnt, nnz);
    bscan_kernel  <<<1, NBP, 0, stream>>>(bcnt, bbase, bcursor, NB, nnz);
    coarse_kernel <<<coarseb, tb, 0, stream>>>(row, col, vals, flags, bcursor, es2, nnz);
    fine_kernel   <<<NB, 512, 0, stream>>>(es2, bbase, es, rp, n, nnz);

    spmm_kernel     <<<rblocks, tb, 0, stream>>>(X0, X1, rp, es, n);
    spmm_kernel     <<<rblocks, tb, 0, stream>>>(X1, X2, rp, es, n);
    spmm_last_kernel<<<rblocks, tb, 0, stream>>>(X2, X1, (float*)d_out, rp, es, n);
}